// Round 18
// baseline (173.683 us; speedup 1.0000x reference)
//
#include <hip/hip_runtime.h>
#include <hip/hip_fp16.h>
#include <stdint.h>

#define M_TOK 8192
#define KD 4096
#define ND 4096

using i32x4 = __attribute__((ext_vector_type(4))) int;
using f32x4 = __attribute__((ext_vector_type(4))) float;

typedef const __attribute__((address_space(1))) void* gp_t;
typedef __attribute__((address_space(3))) void* lp_t;

// ---------------- Kernel 1: fused per-token quant (blocks 0..8191) + weight pack (blocks 8192..) ----------------
__global__ __launch_bounds__(256) void prep_kernel(
    const float* __restrict__ x,
    int8_t* __restrict__ q,
    float* __restrict__ scales,
    const int* __restrict__ w32,
    int8_t* __restrict__ w8)
{
    const int t = threadIdx.x;
    if (blockIdx.x >= 8192) {
        const int b = blockIdx.x - 8192;          // 0..4095
        const int4* w4 = (const int4*)w32;
        int* q32 = (int*)w8;
        #pragma unroll
        for (int u = 0; u < 4; ++u) {
            int g = b * 1024 + u * 256 + t;
            int4 a = w4[g];
            q32[g] = (a.x & 255) | ((a.y & 255) << 8) | ((a.z & 255) << 16) | (a.w << 24);
        }
        return;
    }

    const int row  = blockIdx.x;
    const int lane = t & 63;
    const int wave = t >> 6;

    const float4* xr = (const float4*)(x + (size_t)row * KD);
    float4 p[4];
    #pragma unroll
    for (int i = 0; i < 4; ++i) p[i] = xr[i * 256 + t];

    float am = 0.0f;
    #pragma unroll
    for (int i = 0; i < 4; ++i) {
        am = fmaxf(am, fmaxf(fmaxf(fabsf(p[i].x), fabsf(p[i].y)),
                             fmaxf(fabsf(p[i].z), fabsf(p[i].w))));
    }
    #pragma unroll
    for (int off = 32; off >= 1; off >>= 1)
        am = fmaxf(am, __shfl_xor(am, off));

    __shared__ float smax[4];
    if (lane == 0) smax[wave] = am;
    __syncthreads();
    am = fmaxf(fmaxf(smax[0], smax[1]), fmaxf(smax[2], smax[3]));

    float s = __half2float(__float2half(am * (1.0f / 127.0f)));
    s = fmaxf(s, 1e-30f);
    const float inv = 1.0f / s;

    int* qr = (int*)(q + (size_t)row * KD);
    #pragma unroll
    for (int i = 0; i < 4; ++i) {
        float vv[4] = {p[i].x, p[i].y, p[i].z, p[i].w};
        int w32v = 0;
        #pragma unroll
        for (int e = 0; e < 4; ++e) {
            float tq = __half2float(__float2half(vv[e] * inv));
            int qi = (int)rintf(tq);
            qi = max(-127, min(127, qi));
            w32v |= (qi & 255) << (8 * e);
        }
        qr[i * 256 + t] = w32v;
    }
    if (t == 0) scales[row] = s;
}

// ---------------- 128x128-tile 4-wave int8 GEMM: 2 co-resident blocks/CU + convoy de-phasing ----------------
// LDS per buffer per operand: [128 rows][128 B], XOR-swizzled: phys_col = col ^ ((row&7)<<4).
// Staged via global_load_lds (linear dest) with inverse-swizzled per-lane GLOBAL source (rule #21).
// Per wave (2x2 grid of 4): output 64x64 = 4mf x 4nf frags of 16x16; acc = 64 regs.
// NEW: staggered start (block-uniform s_sleep, 4 classes) breaks the phase-locked convoy of the
// two co-resident blocks so one block's ds_read phase overlaps the other's MFMA phase.

__device__ __forceinline__ void read_Af(const char* lA, int wr, int lane, i32x4 (&a)[4][2]) {
    const int l15 = lane & 15;
    const int cg  = (lane >> 4) << 4;
    #pragma unroll
    for (int mf = 0; mf < 4; ++mf) {
        const int row = wr * 64 + mf * 16 + l15;
        const int sw  = (row & 7) << 4;
        #pragma unroll
        for (int ks = 0; ks < 2; ++ks)
            a[mf][ks] = *(const i32x4*)(lA + row * 128 + ((ks * 64 + cg) ^ sw));
    }
}

__device__ __forceinline__ void read_Bf(const char* lB, int wc, int lane, i32x4 (&b)[4][2]) {
    const int l15 = lane & 15;
    const int cg  = (lane >> 4) << 4;
    #pragma unroll
    for (int nf = 0; nf < 4; ++nf) {
        const int row = wc * 64 + nf * 16 + l15;
        const int sw  = (row & 7) << 4;
        #pragma unroll
        for (int ks = 0; ks < 2; ++ks)
            b[nf][ks] = *(const i32x4*)(lB + row * 128 + ((ks * 64 + cg) ^ sw));
    }
}

// 32 MFMA in one setprio region; ks OUTER so runs of 16 are independent.
__device__ __forceinline__ void mfma_32(i32x4 (&acc)[4][4],
                                        const i32x4 (&a)[4][2],
                                        const i32x4 (&b)[4][2]) {
    __builtin_amdgcn_s_setprio(1);
    #pragma unroll
    for (int ks = 0; ks < 2; ++ks)
        #pragma unroll
        for (int mf = 0; mf < 4; ++mf)
            #pragma unroll
            for (int nf = 0; nf < 4; ++nf)
                acc[mf][nf] = __builtin_amdgcn_mfma_i32_16x16x64_i8(a[mf][ks], b[nf][ks],
                                                                    acc[mf][nf], 0, 0, 0);
    __builtin_amdgcn_s_setprio(0);
}

#define BAR()   __builtin_amdgcn_s_barrier()
#define LGKM0() asm volatile("s_waitcnt lgkmcnt(0)" ::: "memory")
#define VM8()   asm volatile("s_waitcnt vmcnt(8)")

__global__ __launch_bounds__(256, 2) void gemm_q8_128_kernel(
    const int8_t* __restrict__ q,
    const int8_t* __restrict__ w8,
    const float* __restrict__ qs,
    const float* __restrict__ wscale,
    const float* __restrict__ bias,
    float* __restrict__ y)
{
    __shared__ char lds[2][2][16384];   // [buf][A/B][128 rows x 128 B] = 64 KiB -> 2 blocks/CU

    const int tid  = threadIdx.x;
    const int lane = tid & 63;
    const int wave = tid >> 6;     // 0..3
    const int wr   = wave >> 1;    // 0..1
    const int wc   = wave & 1;     // 0..1
    const int tn   = blockIdx.x;   // 0..31
    const int tm   = blockIdx.y;   // 0..63

    // ---- convoy de-phasing: block-uniform staggered start (timing-only, no correctness surface)
    {
        const int stg = ((tn * 0x9E37 + tm * 0x85EB) >> 4) & 3;
        if (stg == 1) asm volatile("s_sleep 8");
        else if (stg == 2) asm volatile("s_sleep 16");
        else if (stg == 3) asm volatile("s_sleep 24");
    }

    const int8_t* gA = q  + (size_t)(tm * 128) * KD;
    const int8_t* gB = w8 + (size_t)(tn * 128) * KD;

    char* lA0 = &lds[0][0][0]; char* lB0 = &lds[0][1][0];
    char* lA1 = &lds[1][0][0]; char* lB1 = &lds[1][1][0];

    // DMA source mapping (inverse swizzle), 4 chunks of 4096 B per operand
    int goff[4];
    #pragma unroll
    for (int ch = 0; ch < 4; ++ch) {
        const int d = ch * 4096 + tid * 16;
        const int r = d >> 7;
        const int cs = (d & 127) ^ ((r & 7) << 4);
        goff[ch] = r * KD + cs;
    }
    const int ldso = tid * 16;

    #define STAGE(gbase, kbyte, ldst)                                                    \
        do {                                                                             \
            const int8_t* _s = (gbase) + (kbyte);                                        \
            __builtin_amdgcn_global_load_lds((gp_t)(_s + goff[0]), (lp_t)((ldst) + ldso),            16, 0, 0); \
            __builtin_amdgcn_global_load_lds((gp_t)(_s + goff[1]), (lp_t)((ldst) + 4096 + ldso),     16, 0, 0); \
            __builtin_amdgcn_global_load_lds((gp_t)(_s + goff[2]), (lp_t)((ldst) + 8192 + ldso),     16, 0, 0); \
            __builtin_amdgcn_global_load_lds((gp_t)(_s + goff[3]), (lp_t)((ldst) + 12288 + ldso),    16, 0, 0); \
        } while (0)

    i32x4 acc[4][4] = {};
    i32x4 a[4][2], b[4][2];

    // prologue: kt0 -> buf0, kt1 -> buf1 (16 loads)
    STAGE(gA, 0,   lA0);
    STAGE(gB, 0,   lB0);
    STAGE(gA, 128, lA1);
    STAGE(gB, 128, lB1);
    VM8();   // kt0 landed
    BAR();

    for (int it = 0; it < 16; ++it) {
        const int kt  = 2 * it;
        const int kb2 = ((kt + 2) & 31) * 128;
        const int kb3 = ((kt + 3) & 31) * 128;

        // even kt: buf0
        read_Af(lA0, wr, lane, a);
        read_Bf(lB0, wc, lane, b);
        LGKM0();                      // own reads landed
        BAR();                        // all waves' reads landed -> safe to overwrite buf0
        STAGE(gA, kb2, lA0);
        STAGE(gB, kb2, lB0);
        mfma_32(acc, a, b);
        VM8();                        // kt+1 (oldest 8) landed
        BAR();

        // odd kt: buf1
        read_Af(lA1, wr, lane, a);
        read_Bf(lB1, wc, lane, b);
        LGKM0();
        BAR();
        STAGE(gA, kb3, lA1);
        STAGE(gB, kb3, lB1);
        mfma_32(acc, a, b);
        VM8();                        // kt+2 (oldest 8) landed -> buf0 ready
        BAR();
    }
    asm volatile("s_waitcnt vmcnt(0)");   // drain wrap-around stages before LDS reuse
    BAR();

    // ---------------- epilogue: scale in-reg, transpose via wave-private LDS, full-line nt stores ----------------
    // wave-private 16 KB region: 64 rows x 64 cols f32 (256 B rows).
    // write byte = rl*256 + ((cl*4) ^ ((rl&7)<<4));  read with same XOR: both <=2-way (free).
    {
        char* myl = &lds[0][0][0] + wave * 16384;
        const int g   = lane >> 4;
        const int l15 = lane & 15;
        #pragma unroll
        for (int mf = 0; mf < 4; ++mf) {
            const int rmb = tm * 128 + wr * 64 + mf * 16 + g * 4;
            float qsv[4];
            #pragma unroll
            for (int r = 0; r < 4; ++r) qsv[r] = qs[rmb + r];
            #pragma unroll
            for (int nf = 0; nf < 4; ++nf) {
                const int n  = tn * 128 + wc * 64 + nf * 16 + l15;
                const float wn = wscale[n];
                const float bn = bias[n];
                const int cl = nf * 16 + l15;
                #pragma unroll
                for (int r = 0; r < 4; ++r) {
                    const int rl = mf * 16 + g * 4 + r;
                    const float val = (float)acc[mf][nf][r] * (qsv[r] * wn) + bn;
                    *(float*)(myl + rl * 256 + ((cl * 4) ^ ((rl & 7) << 4))) = val;
                }
            }
        }
        __builtin_amdgcn_s_barrier();   // keep waves phase-aligned
        const int gcol = tn * 128 + wc * 64 + l15 * 4;
        #pragma unroll
        for (int k = 0; k < 16; ++k) {
            const int rl = g + k * 4;
            const f32x4 v = *(const f32x4*)(myl + rl * 256 + ((l15 * 16) ^ ((rl & 7) << 4)));
            const int grow = tm * 128 + wr * 64 + rl;
            __builtin_nontemporal_store(v, (f32x4*)(y + (size_t)grow * ND + gcol));
        }
    }
    #undef STAGE
}

// ---------------- Fallback GEMM (no-workspace path): 128^2 m97 structure, reads w32 ----------------
__global__ __launch_bounds__(256, 2) void gemm_q8_fallback(
    const int8_t* __restrict__ q,
    const int* __restrict__ w32,
    const float* __restrict__ qs,
    const float* __restrict__ wscale,
    const float* __restrict__ bias,
    float* __restrict__ y)
{
    __shared__ int8_t lA[128 * 64];
    __shared__ int8_t lB[128 * 64];

    const int tid  = threadIdx.x;
    const int lane = tid & 63;
    const int wave = tid >> 6;
    const int wr   = wave >> 1;
    const int wc   = wave & 1;
    const int tn   = blockIdx.x;
    const int tm   = blockIdx.y;

    const int ci0  = wave * 2;
    const int off0 = ci0 * 1024 + lane * 16;
    const int r0   = off0 >> 6;
    const int c0   = off0 & 63;
    const int off1 = off0 + 1024;
    const int r1   = off1 >> 6;
    const int c1   = off1 & 63;

    const int8_t* gA0 = q + (size_t)(tm * 128 + r0) * KD + c0;
    const int8_t* gA1 = q + (size_t)(tm * 128 + r1) * KD + c1;

    const int brow  = tid >> 1;
    const int bhalf = tid & 1;
    const int* gW = w32 + (size_t)(tn * 128 + brow) * KD + bhalf * 32;

    i32x4 acc[4][4] = {};
    const int kc = (lane >> 4) * 16;
    const int rA = wr * 64 + (lane & 15);
    const int rB = wc * 64 + (lane & 15);

    for (int k0 = 0; k0 < KD; k0 += 64) {
        __builtin_amdgcn_global_load_lds((gp_t)(gA0 + k0), (lp_t)(lA + ci0 * 1024),        16, 0, 0);
        __builtin_amdgcn_global_load_lds((gp_t)(gA1 + k0), (lp_t)(lA + ci0 * 1024 + 1024), 16, 0, 0);
        int bw[8];
        #pragma unroll
        for (int u = 0; u < 8; ++u) {
            i32x4 a4 = *(const i32x4*)(gW + k0 + u * 4);
            bw[u] = (a4[0] & 255) | ((a4[1] & 255) << 8) | ((a4[2] & 255) << 16) | (a4[3] << 24);
        }
        *(i32x4*)(lB + brow * 64 + bhalf * 32)      = i32x4{bw[0], bw[1], bw[2], bw[3]};
        *(i32x4*)(lB + brow * 64 + bhalf * 32 + 16) = i32x4{bw[4], bw[5], bw[6], bw[7]};
        __syncthreads();

        i32x4 a[4], b[4];
        #pragma unroll
        for (int i = 0; i < 4; ++i) a[i] = *(const i32x4*)(lA + (rA + i * 16) * 64 + kc);
        #pragma unroll
        for (int j = 0; j < 4; ++j) b[j] = *(const i32x4*)(lB + (rB + j * 16) * 64 + kc);
        #pragma unroll
        for (int i = 0; i < 4; ++i)
            #pragma unroll
            for (int j = 0; j < 4; ++j)
                acc[i][j] = __builtin_amdgcn_mfma_i32_16x16x64_i8(a[i], b[j], acc[i][j], 0, 0, 0);
        __syncthreads();
    }

    const int cbase = tn * 128 + wc * 64 + (lane & 15);
    const int rbase = tm * 128 + wr * 64 + ((lane >> 4) << 2);
    #pragma unroll
    for (int j = 0; j < 4; ++j) {
        const int n  = cbase + j * 16;
        const float wn = wscale[n];
        const float bn = bias[n];
        #pragma unroll
        for (int i = 0; i < 4; ++i)
            #pragma unroll
            for (int r = 0; r < 4; ++r) {
                const int m = rbase + i * 16 + r;
                y[(size_t)m * ND + n] = (float)acc[i][j][r] * (qs[m] * wn) + bn;
            }
    }
}

extern "C" void kernel_launch(void* const* d_in, const int* in_sizes, int n_in,
                              void* d_out, int out_size, void* d_ws, size_t ws_size,
                              hipStream_t stream) {
    const float* x      = (const float*)d_in[0];
    const int*   w32    = (const int*)d_in[1];
    const float* wscale = (const float*)d_in[2];
    const float* bias   = (const float*)d_in[3];
    float*       y      = (float*)d_out;

    const size_t q_bytes  = (size_t)M_TOK * KD;
    const size_t s_bytes  = (size_t)M_TOK * sizeof(float);
    const size_t w8_bytes = (size_t)ND * KD;

    int8_t* qbuf   = (int8_t*)d_ws;
    float*  scales = (float*)((char*)d_ws + q_bytes);
    int8_t* w8     = (int8_t*)((char*)d_ws + q_bytes + s_bytes);

    if (ws_size >= q_bytes + s_bytes + w8_bytes) {
        prep_kernel<<<8192 + 4096, 256, 0, stream>>>(x, qbuf, scales, w32, w8);
        dim3 grid(ND / 128, M_TOK / 128);
        gemm_q8_128_kernel<<<grid, 256, 0, stream>>>(qbuf, w8, scales, wscale, bias, y);
    } else {
        prep_kernel<<<8192, 256, 0, stream>>>(x, qbuf, scales, w32, w8);
        dim3 grid(ND / 128, M_TOK / 128);
        gemm_q8_fallback<<<grid, 256, 0, stream>>>(qbuf, w32, scales, wscale, bias, y);
    }
}

// Round 19
// 166.535 us; speedup vs baseline: 1.0429x; 1.0429x over previous
//
#include <hip/hip_runtime.h>
#include <hip/hip_fp16.h>
#include <stdint.h>

#define M_TOK 8192
#define KD 4096
#define ND 4096

using i32x4 = __attribute__((ext_vector_type(4))) int;
using f32x4 = __attribute__((ext_vector_type(4))) float;

typedef const __attribute__((address_space(1))) void* gp_t;
typedef __attribute__((address_space(3))) void* lp_t;

// ---------------- Kernel 1: fused per-token quant (blocks 0..8191) + weight pack (blocks 8192..) ----------------
__global__ __launch_bounds__(256) void prep_kernel(
    const float* __restrict__ x,
    int8_t* __restrict__ q,
    float* __restrict__ scales,
    const int* __restrict__ w32,
    int8_t* __restrict__ w8)
{
    const int t = threadIdx.x;
    if (blockIdx.x >= 8192) {
        const int b = blockIdx.x - 8192;          // 0..4095
        const int4* w4 = (const int4*)w32;
        int* q32 = (int*)w8;
        #pragma unroll
        for (int u = 0; u < 4; ++u) {
            int g = b * 1024 + u * 256 + t;
            int4 a = w4[g];
            q32[g] = (a.x & 255) | ((a.y & 255) << 8) | ((a.z & 255) << 16) | (a.w << 24);
        }
        return;
    }

    const int row  = blockIdx.x;
    const int lane = t & 63;
    const int wave = t >> 6;

    const float4* xr = (const float4*)(x + (size_t)row * KD);
    float4 p[4];
    #pragma unroll
    for (int i = 0; i < 4; ++i) p[i] = xr[i * 256 + t];

    float am = 0.0f;
    #pragma unroll
    for (int i = 0; i < 4; ++i) {
        am = fmaxf(am, fmaxf(fmaxf(fabsf(p[i].x), fabsf(p[i].y)),
                             fmaxf(fabsf(p[i].z), fabsf(p[i].w))));
    }
    #pragma unroll
    for (int off = 32; off >= 1; off >>= 1)
        am = fmaxf(am, __shfl_xor(am, off));

    __shared__ float smax[4];
    if (lane == 0) smax[wave] = am;
    __syncthreads();
    am = fmaxf(fmaxf(smax[0], smax[1]), fmaxf(smax[2], smax[3]));

    float s = __half2float(__float2half(am * (1.0f / 127.0f)));
    s = fmaxf(s, 1e-30f);
    const float inv = 1.0f / s;

    int* qr = (int*)(q + (size_t)row * KD);
    #pragma unroll
    for (int i = 0; i < 4; ++i) {
        float vv[4] = {p[i].x, p[i].y, p[i].z, p[i].w};
        int w32v = 0;
        #pragma unroll
        for (int e = 0; e < 4; ++e) {
            float tq = __half2float(__float2half(vv[e] * inv));
            int qi = (int)rintf(tq);
            qi = max(-127, min(127, qi));
            w32v |= (qi & 255) << (8 * e);
        }
        qr[i * 256 + t] = w32v;
    }
    if (t == 0) scales[row] = s;
}

// ---------------- 4-phase 256x256 int8 GEMM (r9/r11 proven schedule, raw barriers) ----------------
// LDS per buffer per operand: [256 rows][128 B], XOR-swizzled: phys_col = col ^ ((row&7)<<4).
// Staged via global_load_lds (linear dest) with inverse-swizzled per-lane GLOBAL source (rule #21).

template<int MH>
__device__ __forceinline__ void read_A(const char* lA, int wr, int lane, i32x4 (&a)[4][2]) {
    const int l15 = lane & 15;
    const int cg  = (lane >> 4) << 4;
    #pragma unroll
    for (int mf = 0; mf < 4; ++mf) {
        const int row = MH * 128 + wr * 64 + mf * 16 + l15;
        const int sw  = (row & 7) << 4;
        #pragma unroll
        for (int ks = 0; ks < 2; ++ks)
            a[mf][ks] = *(const i32x4*)(lA + row * 128 + ((ks * 64 + cg) ^ sw));
    }
}

template<int NH>
__device__ __forceinline__ void read_B(const char* lB, int wc, int lane, i32x4 (&b)[2][2]) {
    const int l15 = lane & 15;
    const int cg  = (lane >> 4) << 4;
    #pragma unroll
    for (int nf = 0; nf < 2; ++nf) {
        const int row = NH * 128 + wc * 32 + nf * 16 + l15;
        const int sw  = (row & 7) << 4;
        #pragma unroll
        for (int ks = 0; ks < 2; ++ks)
            b[nf][ks] = *(const i32x4*)(lB + row * 128 + ((ks * 64 + cg) ^ sw));
    }
}

// 32 MFMA (one M-half x full N) in one setprio region; ks OUTER so runs of 16 are independent.
template<int MH>
__device__ __forceinline__ void mfma_half(i32x4 (&acc)[2][4][2][2],
                                          const i32x4 (&a)[4][2],
                                          const i32x4 (&b0)[2][2],
                                          const i32x4 (&b1)[2][2]) {
    __builtin_amdgcn_s_setprio(1);
    #pragma unroll
    for (int ks = 0; ks < 2; ++ks)
        #pragma unroll
        for (int mf = 0; mf < 4; ++mf) {
            #pragma unroll
            for (int nf = 0; nf < 2; ++nf)
                acc[MH][mf][0][nf] =
                    __builtin_amdgcn_mfma_i32_16x16x64_i8(a[mf][ks], b0[nf][ks],
                                                          acc[MH][mf][0][nf], 0, 0, 0);
            #pragma unroll
            for (int nf = 0; nf < 2; ++nf)
                acc[MH][mf][1][nf] =
                    __builtin_amdgcn_mfma_i32_16x16x64_i8(a[mf][ks], b1[nf][ks],
                                                          acc[MH][mf][1][nf], 0, 0, 0);
        }
    __builtin_amdgcn_s_setprio(0);
}

#define BAR() __builtin_amdgcn_s_barrier()

__global__ __launch_bounds__(512, 2) void gemm_q8_4ph_kernel(
    const int8_t* __restrict__ q,
    const int8_t* __restrict__ w8,
    const float* __restrict__ qs,
    const float* __restrict__ wscale,
    const float* __restrict__ bias,
    float* __restrict__ y)
{
    __shared__ char lds[2][2][32768];   // [buf][A/B][256 rows x 128 B]

    const int tid  = threadIdx.x;
    const int lane = tid & 63;
    const int wave = tid >> 6;
    const int wr   = wave >> 2;   // 0..1
    const int wc   = wave & 3;    // 0..3
    const int tn   = blockIdx.x;  // 0..15
    const int tm   = blockIdx.y;  // 0..31

    const int8_t* gA = q  + (size_t)(tm * 256) * KD;
    const int8_t* gB = w8 + (size_t)(tn * 256) * KD;

    char* lA0 = &lds[0][0][0]; char* lB0 = &lds[0][1][0];
    char* lA1 = &lds[1][0][0]; char* lB1 = &lds[1][1][0];

    // loop-invariant staging address parts
    int goff[2];
    #pragma unroll
    for (int qq = 0; qq < 2; ++qq) {
        const int d = qq * 8192 + wave * 1024 + lane * 16;
        const int r = d >> 7;
        const int cs = (d & 127) ^ ((r & 7) << 4);
        goff[qq] = r * KD + cs;
    }
    const int ldso = wave * 1024;

    #define STAGE(gbase, half, kbyte, ldst)                                              \
        do {                                                                             \
            const int8_t* _s = (gbase) + (size_t)(half) * 128 * KD + (kbyte);            \
            __builtin_amdgcn_global_load_lds((gp_t)(_s + goff[0]),                       \
                (lp_t)((ldst) + (half) * 16384 + ldso), 16, 0, 0);                       \
            __builtin_amdgcn_global_load_lds((gp_t)(_s + goff[1]),                       \
                (lp_t)((ldst) + (half) * 16384 + 8192 + ldso), 16, 0, 0);                \
        } while (0)

    i32x4 acc[2][4][2][2] = {};
    i32x4 a[4][2], b0[2][2], b1[2][2];

    // prologue: kt0 full -> buf0 ; kt1 A0,B0 -> buf1  (12 loads)
    STAGE(gA, 0, 0,   lA0);
    STAGE(gB, 0, 0,   lB0);
    STAGE(gA, 1, 0,   lA0);
    STAGE(gB, 1, 0,   lB0);
    STAGE(gA, 0, 128, lA1);
    STAGE(gB, 0, 128, lB1);
    asm volatile("s_waitcnt vmcnt(4)");   // kt=0 fully landed
    BAR();

    for (int it = 0; it < 15; ++it) {
        const int kt  = 2 * it;
        const int kb1 = (kt + 1) * 128;
        const int kb2 = (kt + 2) * 128;
        const int kb3 = (kt + 3) * 128;

        // P1: read A0,B0,B1 (buf0,kt); stage A1,B1(kt+1)->buf1; 32 MFMA (mh=0)
        read_A<0>(lA0, wr, lane, a);
        read_B<0>(lB0, wc, lane, b0);
        read_B<1>(lB0, wc, lane, b1);
        STAGE(gA, 1, kb1, lA1);
        STAGE(gB, 1, kb1, lB1);
        BAR();
        mfma_half<0>(acc, a, b0, b1);
        asm volatile("s_waitcnt vmcnt(4)");   // kt+1 A0,B0 landed
        BAR();

        // P2: read A1 (buf0,kt); stage A0,B0(kt+2)->buf0; 32 MFMA (mh=1)
        read_A<1>(lA0, wr, lane, a);
        STAGE(gA, 0, kb2, lA0);
        STAGE(gB, 0, kb2, lB0);
        BAR();
        mfma_half<1>(acc, a, b0, b1);
        asm volatile("s_waitcnt vmcnt(4)");   // kt+1 A1,B1 landed
        BAR();

        // P3: read A0,B0,B1 (buf1,kt+1); stage A1,B1(kt+2)->buf0; 32 MFMA (mh=0)
        read_A<0>(lA1, wr, lane, a);
        read_B<0>(lB1, wc, lane, b0);
        read_B<1>(lB1, wc, lane, b1);
        STAGE(gA, 1, kb2, lA0);
        STAGE(gB, 1, kb2, lB0);
        BAR();
        mfma_half<0>(acc, a, b0, b1);
        asm volatile("s_waitcnt vmcnt(4)");   // kt+2 A0,B0 landed
        BAR();

        // P4: read A1 (buf1,kt+1); stage A0,B0(kt+3)->buf1; 32 MFMA (mh=1)
        read_A<1>(lA1, wr, lane, a);
        STAGE(gA, 0, kb3, lA1);
        STAGE(gB, 0, kb3, lB1);
        BAR();
        mfma_half<1>(acc, a, b0, b1);
        asm volatile("s_waitcnt vmcnt(4)");   // kt+2 A1,B1 landed -> buf0 ready
        BAR();
    }

    // peeled last iteration (kt=30,31): only P1's stage is real; drains DMA fully
    {
        const int kb1 = 31 * 128;
        read_A<0>(lA0, wr, lane, a);
        read_B<0>(lB0, wc, lane, b0);
        read_B<1>(lB0, wc, lane, b1);
        STAGE(gA, 1, kb1, lA1);
        STAGE(gB, 1, kb1, lB1);
        BAR();
        mfma_half<0>(acc, a, b0, b1);
        BAR();

        read_A<1>(lA0, wr, lane, a);
        BAR();
        mfma_half<1>(acc, a, b0, b1);
        asm volatile("s_waitcnt vmcnt(0)");   // everything landed; no DMA in flight past here
        BAR();

        read_A<0>(lA1, wr, lane, a);
        read_B<0>(lB1, wc, lane, b0);
        read_B<1>(lB1, wc, lane, b1);
        BAR();
        mfma_half<0>(acc, a, b0, b1);
        BAR();

        read_A<1>(lA1, wr, lane, a);
        BAR();
        mfma_half<1>(acc, a, b0, b1);
        BAR();   // all waves done reading LDS -> safe to reuse for epilogue
    }

    // ---------------- epilogue: scale in-reg, transpose via wave-private LDS, full-line nt stores ----------------
    // wave-private 16 KB region; per nh pass: 128 rows x 32 cols f32.
    // LDS byte = rl*128 + ((cl*4) ^ ((rl&7)<<4)) : writes and reads both conflict-free.
    {
        char* myl = &lds[0][0][0] + wave * 16384;
        const int g   = lane >> 4;
        const int l15 = lane & 15;
        #pragma unroll
        for (int nh = 0; nh < 2; ++nh) {
            #pragma unroll
            for (int mh = 0; mh < 2; ++mh)
                #pragma unroll
                for (int mf = 0; mf < 4; ++mf) {
                    const int rmb = tm * 256 + mh * 128 + wr * 64 + mf * 16 + g * 4;
                    float qsv[4];
                    #pragma unroll
                    for (int r = 0; r < 4; ++r) qsv[r] = qs[rmb + r];
                    #pragma unroll
                    for (int nf = 0; nf < 2; ++nf) {
                        const int n  = tn * 256 + nh * 128 + wc * 32 + nf * 16 + l15;
                        const float wn = wscale[n];
                        const float bn = bias[n];
                        const int cl = nf * 16 + l15;
                        #pragma unroll
                        for (int r = 0; r < 4; ++r) {
                            const int rl = mh * 64 + mf * 16 + g * 4 + r;
                            const float val = (float)acc[mh][mf][nh][nf][r] * (qsv[r] * wn) + bn;
                            *(float*)(myl + rl * 128 + ((cl * 4) ^ ((rl & 7) << 4))) = val;
                        }
                    }
                }
            __builtin_amdgcn_s_barrier();   // keep waves phase-aligned
            // read back one full row per 8 lanes; nt store 8 full 128B lines per instruction
            const int gcol = tn * 256 + nh * 128 + wc * 32 + (lane & 7) * 4;
            #pragma unroll
            for (int k = 0; k < 16; ++k) {
                const int rl = (lane >> 3) + k * 8;
                const f32x4 v = *(const f32x4*)(myl + rl * 128 + (((lane & 7) * 16) ^ ((rl & 7) << 4)));
                const int grow = tm * 256 + (rl >> 6) * 128 + wr * 64 + (rl & 63);
                __builtin_nontemporal_store(v, (f32x4*)(y + (size_t)grow * ND + gcol));
            }
            __builtin_amdgcn_s_barrier();
        }
    }
    #undef STAGE
}

// ---------------- Fallback GEMM (no-workspace path): 128^2 m97 structure, reads w32 ----------------
__global__ __launch_bounds__(256, 2) void gemm_q8_fallback(
    const int8_t* __restrict__ q,
    const int* __restrict__ w32,
    const float* __restrict__ qs,
    const float* __restrict__ wscale,
    const float* __restrict__ bias,
    float* __restrict__ y)
{
    __shared__ int8_t lA[128 * 64];
    __shared__ int8_t lB[128 * 64];

    const int tid  = threadIdx.x;
    const int lane = tid & 63;
    const int wave = tid >> 6;
    const int wr   = wave >> 1;
    const int wc   = wave & 1;
    const int tn   = blockIdx.x;
    const int tm   = blockIdx.y;

    const int ci0  = wave * 2;
    const int off0 = ci0 * 1024 + lane * 16;
    const int r0   = off0 >> 6;
    const int c0   = off0 & 63;
    const int off1 = off0 + 1024;
    const int r1   = off1 >> 6;
    const int c1   = off1 & 63;

    const int8_t* gA0 = q + (size_t)(tm * 128 + r0) * KD + c0;
    const int8_t* gA1 = q + (size_t)(tm * 128 + r1) * KD + c1;

    const int brow  = tid >> 1;
    const int bhalf = tid & 1;
    const int* gW = w32 + (size_t)(tn * 128 + brow) * KD + bhalf * 32;

    i32x4 acc[4][4] = {};
    const int kc = (lane >> 4) * 16;
    const int rA = wr * 64 + (lane & 15);
    const int rB = wc * 64 + (lane & 15);

    for (int k0 = 0; k0 < KD; k0 += 64) {
        __builtin_amdgcn_global_load_lds((gp_t)(gA0 + k0), (lp_t)(lA + ci0 * 1024),        16, 0, 0);
        __builtin_amdgcn_global_load_lds((gp_t)(gA1 + k0), (lp_t)(lA + ci0 * 1024 + 1024), 16, 0, 0);
        int bw[8];
        #pragma unroll
        for (int u = 0; u < 8; ++u) {
            i32x4 a4 = *(const i32x4*)(gW + k0 + u * 4);
            bw[u] = (a4[0] & 255) | ((a4[1] & 255) << 8) | ((a4[2] & 255) << 16) | (a4[3] << 24);
        }
        *(i32x4*)(lB + brow * 64 + bhalf * 32)      = i32x4{bw[0], bw[1], bw[2], bw[3]};
        *(i32x4*)(lB + brow * 64 + bhalf * 32 + 16) = i32x4{bw[4], bw[5], bw[6], bw[7]};
        __syncthreads();

        i32x4 a[4], b[4];
        #pragma unroll
        for (int i = 0; i < 4; ++i) a[i] = *(const i32x4*)(lA + (rA + i * 16) * 64 + kc);
        #pragma unroll
        for (int j = 0; j < 4; ++j) b[j] = *(const i32x4*)(lB + (rB + j * 16) * 64 + kc);
        #pragma unroll
        for (int i = 0; i < 4; ++i)
            #pragma unroll
            for (int j = 0; j < 4; ++j)
                acc[i][j] = __builtin_amdgcn_mfma_i32_16x16x64_i8(a[i], b[j], acc[i][j], 0, 0, 0);
        __syncthreads();
    }

    const int cbase = tn * 128 + wc * 64 + (lane & 15);
    const int rbase = tm * 128 + wr * 64 + ((lane >> 4) << 2);
    #pragma unroll
    for (int j = 0; j < 4; ++j) {
        const int n  = cbase + j * 16;
        const float wn = wscale[n];
        const float bn = bias[n];
        #pragma unroll
        for (int i = 0; i < 4; ++i)
            #pragma unroll
            for (int r = 0; r < 4; ++r) {
                const int m = rbase + i * 16 + r;
                y[(size_t)m * ND + n] = (float)acc[i][j][r] * (qs[m] * wn) + bn;
            }
    }
}

extern "C" void kernel_launch(void* const* d_in, const int* in_sizes, int n_in,
                              void* d_out, int out_size, void* d_ws, size_t ws_size,
                              hipStream_t stream) {
    const float* x      = (const float*)d_in[0];
    const int*   w32    = (const int*)d_in[1];
    const float* wscale = (const float*)d_in[2];
    const float* bias   = (const float*)d_in[3];
    float*       y      = (float*)d_out;

    const size_t q_bytes  = (size_t)M_TOK * KD;
    const size_t s_bytes  = (size_t)M_TOK * sizeof(float);
    const size_t w8_bytes = (size_t)ND * KD;

    int8_t* qbuf   = (int8_t*)d_ws;
    float*  scales = (float*)((char*)d_ws + q_bytes);
    int8_t* w8     = (int8_t*)((char*)d_ws + q_bytes + s_bytes);

    if (ws_size >= q_bytes + s_bytes + w8_bytes) {
        prep_kernel<<<8192 + 4096, 256, 0, stream>>>(x, qbuf, scales, w32, w8);
        dim3 grid(ND / 256, M_TOK / 256);
        gemm_q8_4ph_kernel<<<grid, 512, 0, stream>>>(qbuf, w8, scales, wscale, bias, y);
    } else {
        prep_kernel<<<8192, 256, 0, stream>>>(x, qbuf, scales, w32, w8);
        dim3 grid(ND / 128, M_TOK / 128);
        gemm_q8_fallback<<<grid, 256, 0, stream>>>(qbuf, w32, scales, wscale, bias, y);
    }
}